// Round 7
// baseline (347.270 us; speedup 1.0000x reference)
//
#include <hip/hip_runtime.h>
#include <math.h>

#define BATCH 4
#define SEQ   4096
#define EMB   1024
#define HD    128
#define MROWS (BATCH*SEQ)
#define SCALE  0.08838834764831844f   // 1/sqrt(128)
#define SCALEQ 0.12751742f            // (1/sqrt(128)) * log2(e)  -> exp2-domain scores
#define CHUNK 10                      // kv-tiles (of 64) per split-KV job
#define NJOBS 119                     // jobs per batch at BQ=128, CHUNK=10
#define MAXC  7                       // max chunks per q-tile = ceil(64/10)

typedef __attribute__((ext_vector_type(8))) short bf16x8;   // MFMA A/B frag (4 VGPR)
typedef __attribute__((ext_vector_type(4))) short short4v;  // 8B LDS store
typedef __attribute__((ext_vector_type(4))) float f32x4;    // MFMA C/D frag
typedef __attribute__((ext_vector_type(4))) int   i32x4;    // 16B copy
typedef __attribute__((ext_vector_type(2))) int   i32x2;    // 8B copy

static __device__ __forceinline__ unsigned short f2bf(float f) {
    unsigned int u = __float_as_uint(f);
    u += 0x7fff + ((u >> 16) & 1);       // RNE
    return (unsigned short)(u >> 16);
}
static __device__ __forceinline__ float bf2f(unsigned short s) {
    return __uint_as_float((unsigned int)s << 16);
}
static __device__ __forceinline__ short4v pack4(float4 a) {
    short4v p;
    p[0] = (short)f2bf(a.x); p[1] = (short)f2bf(a.y);
    p[2] = (short)f2bf(a.z); p[3] = (short)f2bf(a.w);
    return p;
}
// HW packed f32->bf16 RNE
static __device__ __forceinline__ int cvtpk(float lo, float hi) {
    int r;
    asm("v_cvt_pk_bf16_f32 %0, %1, %2" : "=v"(r) : "v"(lo), "v"(hi));
    return r;
}
// async global->LDS, 16B/lane: dest = wave-uniform base + lane*16 (linear)
static __device__ __forceinline__ void gload_lds16(const unsigned short* g, unsigned short* l) {
    __builtin_amdgcn_global_load_lds(
        (const __attribute__((address_space(1))) void*)g,
        (__attribute__((address_space(3))) void*)l, 16, 0, 0);
}

// ---------------- W transpose + bf16 -> FRAGMENT-CONTIGUOUS layout ----------------
__global__ __launch_bounds__(256) void wtrans_kernel(
    const float* __restrict__ Wq, const float* __restrict__ Wk,
    const float* __restrict__ Wv, unsigned short* __restrict__ Wt)
{
    __shared__ __align__(16) unsigned short Xs[16 * 132];
    const int w  = blockIdx.y;
    const float* W = (w == 0) ? Wq : (w == 1) ? Wk : Wv;
    const float sc = (w == 0) ? SCALEQ : 1.0f;   // exp2-domain: scores carry log2(e)
    const int bx = blockIdx.x;
    const int k0 = bx * 16;
    const int t  = threadIdx.x;

#pragma unroll
    for (int i = 0; i < 2; ++i) {
        int gg = i * 256 + t;                 // 0..511
        int row = gg >> 5, c4 = gg & 31;
        float4 a = *(const float4*)&W[(size_t)(k0 + row) * HD + c4 * 4];
        short4v p;
        p[0] = (short)f2bf(a.x * sc); p[1] = (short)f2bf(a.y * sc);
        p[2] = (short)f2bf(a.z * sc); p[3] = (short)f2bf(a.w * sc);
        *(short4v*)&Xs[row * 132 + c4 * 4] = p;
    }
    __syncthreads();
    const int n = t >> 1, g = t & 1;
    i32x4 o;
#pragma unroll
    for (int e = 0; e < 4; ++e) {
        unsigned int lo = Xs[(g * 8 + e * 2    ) * 132 + n];
        unsigned int hi = Xs[(g * 8 + e * 2 + 1) * 132 + n];
        o[e] = (int)(lo | (hi << 16));
    }
    const int ntg  = w * 8 + (n >> 4);
    const int kc   = bx >> 1;
    const int quad = (bx * 2 + g) & 3;
    const int lane = quad * 16 + (n & 15);
    *(i32x4*)&Wt[(((size_t)ntg * 32 + kc) * 64 + lane) * 8] = o;
}

// ---------------- Fused QKV (unchanged from round 5) ----------------
__global__ __launch_bounds__(512, 2) void qkv_kernel(
    const float* __restrict__ x, const unsigned short* __restrict__ Wt,
    unsigned short* __restrict__ qb, unsigned short* __restrict__ kb,
    unsigned short* __restrict__ vtb)
{
    __shared__ __align__(1024) unsigned short lds[58368];  // W dbuf 96KB + x dbuf 18.4KB
    unsigned short* Ws  = lds;
    unsigned short* xsA = lds + 49152;
    unsigned short* xsB = lds + 53760;

    const int t    = threadIdx.x;
    const int lane = t & 63, ng = t >> 6;
    const int quad = lane >> 4, l16 = lane & 15;
    const int m0   = blockIdx.x * 64;

    f32x4 acc[4][3];
#pragma unroll
    for (int i = 0; i < 4; ++i)
#pragma unroll
        for (int j = 0; j < 3; ++j) acc[i][j] = (f32x4){0.f, 0.f, 0.f, 0.f};

    const int xr0 = t >> 4,         xc0 = (t & 15) * 4;
    const int xr1 = (t + 512) >> 4, xc1 = ((t + 512) & 15) * 4;
    const float* xb0 = x + (size_t)(m0 + xr0) * EMB + xc0;
    const float* xb1 = x + (size_t)(m0 + xr1) * EMB + xc1;

    const unsigned short* Wg = Wt + (size_t)lane * 8;
    float4 xra, xrb;

    {
        float4 a = *(const float4*)&xb0[0];
        float4 b = *(const float4*)&xb1[0];
        *(short4v*)&xsA[xr0 * 72 + xc0] = pack4(a);
        *(short4v*)&xsA[xr1 * 72 + xc1] = pack4(b);
#pragma unroll
        for (int jt = 0; jt < 3; ++jt)
#pragma unroll
            for (int kcl = 0; kcl < 2; ++kcl) {
                int ntg = ng * 3 + jt;
                gload_lds16(Wg + ((size_t)ntg * 32 + kcl) * 512,
                            Ws + ((size_t)ntg * 2 + kcl) * 512);
            }
        xra = *(const float4*)&xb0[64];
        xrb = *(const float4*)&xb1[64];
    }
    asm volatile("s_waitcnt vmcnt(2)" ::: "memory");
    asm volatile("s_waitcnt lgkmcnt(0)" ::: "memory");
    __builtin_amdgcn_s_barrier();

    for (int ph = 0; ph < 16; ++ph) {
        const int cb = ph & 1, nb = cb ^ 1;
        unsigned short* xc = cb ? xsB : xsA;
        unsigned short* xn = cb ? xsA : xsB;
        const int kcn = (ph < 15 ? ph + 1 : 15) * 2;

#pragma unroll
        for (int jt = 0; jt < 3; ++jt)
#pragma unroll
            for (int kcl = 0; kcl < 2; ++kcl) {
                int ntg = ng * 3 + jt;
                gload_lds16(Wg + ((size_t)ntg * 32 + kcn + kcl) * 512,
                            Ws + ((size_t)(nb * 48) + ntg * 2 + kcl) * 512);
            }
        *(short4v*)&xn[xr0 * 72 + xc0] = pack4(xra);
        *(short4v*)&xn[xr1 * 72 + xc1] = pack4(xrb);
        {
            const int xcol = (ph + 2 < 16) ? (ph + 2) * 64 : 960;
            xra = *(const float4*)&xb0[xcol];
            xrb = *(const float4*)&xb1[xcol];
        }
        {
            bf16x8 aA[2][4], aB[2][3];
#pragma unroll
            for (int ks = 0; ks < 2; ++ks)
#pragma unroll
                for (int jt = 0; jt < 3; ++jt)
                    aB[ks][jt] = *(const bf16x8*)&Ws[((size_t)(cb * 48) + (ng * 3 + jt) * 2 + ks) * 512 + lane * 8];
#pragma unroll
            for (int ks = 0; ks < 2; ++ks)
#pragma unroll
                for (int mt = 0; mt < 4; ++mt)
                    aA[ks][mt] = *(const bf16x8*)&xc[(mt * 16 + l16) * 72 + ks * 32 + quad * 8];
            __builtin_amdgcn_s_setprio(1);
#pragma unroll
            for (int ks = 0; ks < 2; ++ks)
#pragma unroll
                for (int mt = 0; mt < 4; ++mt)
#pragma unroll
                    for (int jt = 0; jt < 3; ++jt)
                        acc[mt][jt] = __builtin_amdgcn_mfma_f32_16x16x32_bf16(
                            aA[ks][mt], aB[ks][jt], acc[mt][jt], 0, 0, 0);
            __builtin_amdgcn_s_setprio(0);
        }
        asm volatile("s_waitcnt vmcnt(2)" ::: "memory");
        asm volatile("s_waitcnt lgkmcnt(0)" ::: "memory");
        __builtin_amdgcn_s_barrier();
    }

    // ---- epilogue ----
    unsigned short* Cq = lds;                 // [64][136]
    unsigned short* Ck = lds + 64 * 136;      // [64][136]
    unsigned short* Cv = lds + 2 * 64 * 136;  // [128][72] transposed
#pragma unroll
    for (int mt = 0; mt < 4; ++mt)
#pragma unroll
        for (int jt = 0; jt < 3; ++jt) {
            int nt = ng * 3 + jt;
            int wm = nt >> 3, nl = nt & 7;
            if (wm < 2) {
                unsigned short* C = (wm == 0) ? Cq : Ck;
#pragma unroll
                for (int rr = 0; rr < 4; ++rr)
                    C[(mt * 16 + quad * 4 + rr) * 136 + nl * 16 + l16] =
                        f2bf(acc[mt][jt][rr]);
            } else {
                i32x2 p;
                p[0] = cvtpk(acc[mt][jt][0], acc[mt][jt][1]);
                p[1] = cvtpk(acc[mt][jt][2], acc[mt][jt][3]);
                *(i32x2*)&Cv[(nl * 16 + l16) * 72 + mt * 16 + quad * 4] = p;
            }
        }
    __syncthreads();
    {
#pragma unroll
        for (int i = 0; i < 2; ++i) {
            int idx = i * 512 + t;
            int row = idx >> 4, seg = idx & 15;
            *(i32x4*)&qb[((size_t)(m0 + row)) * HD + seg * 8] = *(const i32x4*)&Cq[row * 136 + seg * 8];
            *(i32x4*)&kb[((size_t)(m0 + row)) * HD + seg * 8] = *(const i32x4*)&Ck[row * 136 + seg * 8];
        }
    }
    {
        const int b = m0 >> 12, s0 = m0 & 4095;
#pragma unroll
        for (int i = 0; i < 2; ++i) {
            int idx = i * 512 + t;
            int h = idx >> 3, seg = idx & 7;
            *(i32x4*)&vtb[(size_t)b * (HD * SEQ) + (size_t)h * SEQ + s0 + seg * 8] =
                *(const i32x4*)&Cv[h * 72 + seg * 8];
        }
    }
}

// ---------------- Flash attention + fused split-K combine (R5 config restored) ----------------
// Round-6 lesson: BQ=64 TLP restructure REGRESSED (occupancy fell; tile-instances
// and barriers doubled). Reverted to BQ=128, 8 waves, 480x512.
// Round-7 change: combine_kernel deleted; last-finishing job per q-tile performs
// the combine in-kernel (atomic counter + device fences). Kills one launch (~10us
// overhead) + runs combine on already-resident blocks, overlapped with tail jobs.
#define PADK 136
#define PADV 72
#define PADP 72
#define DEFER_THR 8.0f   // log2 domain: P bounded by 2^8=256, safe in bf16/f32

__global__ __launch_bounds__(512, 4) void flash_kernel(
    const unsigned short* __restrict__ qb, const unsigned short* __restrict__ kb,
    const unsigned short* __restrict__ vtb, unsigned short* __restrict__ Opart,
    float* __restrict__ mbuf, float* __restrict__ lbuf,
    unsigned int* __restrict__ ctr, float* __restrict__ out)
{
    __shared__ __align__(16) unsigned short Ks[64 * PADK];    // 17.4 KB
    __shared__ __align__(16) unsigned short Vt[128 * PADV];   // 18.4 KB
    __shared__ __align__(16) unsigned short Pt[128 * PADP];   // 18.4 KB
    __shared__ int lastFlag;

    const int bx   = blockIdx.x;
    const int slot = bx & 7, pp = bx >> 3;
    const int b    = slot >> 1;
    const int jj   = pp * 2 + (slot & 1);
    if (jj >= NJOBS) return;

    const int t    = threadIdx.x;
    const int lane = t & 63, w = t >> 6;     // 8 waves
    const int quad = lane >> 4, l16 = lane & 15;

    // decode jj -> (qi, c): q-tile qi has ceil((qi+1)/5) chunks; s = first jj of qi
    int qi = 0, s = 0;
    for (qi = 0; qi < 32; ++qi) {
        int cnt = (qi + 5) / 5;
        if (jj < s + cnt) break;
        s += cnt;
    }
    const int c    = jj - s;
    const int nc   = (qi + 5) / 5;
    const int qrow = qi * 128 + w * 16 + l16;
    const int jmax = 2 * qi + 2;
    const int jbeg = c * CHUNK;
    const int jend = min(jbeg + CHUNK, jmax);
    const int wtop = qi * 128 + w * 16;      // wave's lowest q-row

    bf16x8 qf[4];
    {
        const unsigned short* qp = qb + ((size_t)b * SEQ + qrow) * HD;
#pragma unroll
        for (int ks = 0; ks < 4; ++ks)
            qf[ks] = *(const bf16x8*)&qp[ks * 32 + quad * 8];
    }

    f32x4 O[8];
#pragma unroll
    for (int i = 0; i < 8; ++i) O[i] = (f32x4){0.f, 0.f, 0.f, 0.f};
    float m_run = -1e30f, l_run = 0.f;

    const unsigned short* kbb  = kb  + (size_t)b * SEQ * HD;
    const unsigned short* vtbb = vtb + (size_t)b * HD * SEQ;

    const int gg0 = t, gg1 = 512 + t;
    i32x4 kr0, kr1, vr0, vr1;
    kr0 = *(const i32x4*)&kbb[(size_t)jbeg * 64 * HD + (size_t)gg0 * 8];
    kr1 = *(const i32x4*)&kbb[(size_t)jbeg * 64 * HD + (size_t)gg1 * 8];
    vr0 = *(const i32x4*)&vtbb[(size_t)(gg0 >> 3) * SEQ + jbeg * 64 + (gg0 & 7) * 8];
    vr1 = *(const i32x4*)&vtbb[(size_t)(gg1 >> 3) * SEQ + jbeg * 64 + (gg1 & 7) * 8];

    for (int j0 = jbeg; j0 < jend; ++j0) {
        __syncthreads();   // prior iteration's reads of Ks/Vt complete (WAR)
        *(i32x4*)&Ks[(gg0 >> 4) * PADK + (gg0 & 15) * 8] = kr0;
        *(i32x4*)&Ks[(gg1 >> 4) * PADK + (gg1 & 15) * 8] = kr1;
        *(i32x4*)&Vt[(gg0 >> 3) * PADV + (gg0 & 7) * 8] = vr0;
        *(i32x4*)&Vt[(gg1 >> 3) * PADV + (gg1 & 7) * 8] = vr1;
        __syncthreads();

        if (j0 + 1 < jend) {
            const int j1 = j0 + 1;
            kr0 = *(const i32x4*)&kbb[(size_t)j1 * 64 * HD + (size_t)gg0 * 8];
            kr1 = *(const i32x4*)&kbb[(size_t)j1 * 64 * HD + (size_t)gg1 * 8];
            vr0 = *(const i32x4*)&vtbb[(size_t)(gg0 >> 3) * SEQ + j1 * 64 + (gg0 & 7) * 8];
            vr1 = *(const i32x4*)&vtbb[(size_t)(gg1 >> 3) * SEQ + j1 * 64 + (gg1 & 7) * 8];
        }

        if (j0 * 64 > wtop + 15) continue;

        // ---- S^T = K . Q^T ----
        f32x4 st[4];
        __builtin_amdgcn_s_setprio(1);
#pragma unroll
        for (int mt = 0; mt < 4; ++mt) {
            f32x4 a = (f32x4){0.f, 0.f, 0.f, 0.f};
#pragma unroll
            for (int ks = 0; ks < 4; ++ks) {
                bf16x8 kf = *(const bf16x8*)&Ks[(mt * 16 + l16) * PADK + ks * 32 + quad * 8];
                a = __builtin_amdgcn_mfma_f32_16x16x32_bf16(kf, qf[ks], a, 0, 0, 0);
            }
            st[mt] = a;
        }
        __builtin_amdgcn_s_setprio(0);

        // ---- causal mask ----
        if (j0 * 64 + 63 > wtop) {
#pragma unroll
            for (int mt = 0; mt < 4; ++mt)
#pragma unroll
                for (int rr = 0; rr < 4; ++rr) {
                    int kv = j0 * 64 + mt * 16 + quad * 4 + rr;
                    if (kv > qrow) st[mt][rr] = -1e30f;
                }
        }

        // ---- online softmax, exp2 domain ----
        float mx = -1e30f;
#pragma unroll
        for (int mt = 0; mt < 4; ++mt)
#pragma unroll
            for (int rr = 0; rr < 4; ++rr) mx = fmaxf(mx, st[mt][rr]);
        mx = fmaxf(mx, __shfl_xor(mx, 16));
        mx = fmaxf(mx, __shfl_xor(mx, 32));
        if (!__all(mx <= m_run + DEFER_THR)) {
            const float m_new = fmaxf(m_run, mx);
            const float alpha = exp2f(m_run - m_new);
            l_run *= alpha;
#pragma unroll
            for (int i = 0; i < 8; ++i) {
                O[i][0] *= alpha; O[i][1] *= alpha; O[i][2] *= alpha; O[i][3] *= alpha;
            }
            m_run = m_new;
        }
        float psum = 0.f;
#pragma unroll
        for (int mt = 0; mt < 4; ++mt)
#pragma unroll
            for (int rr = 0; rr < 4; ++rr) {
                float p = exp2f(st[mt][rr] - m_run);
                st[mt][rr] = p;
                psum += p;
            }
        psum += __shfl_xor(psum, 16);
        psum += __shfl_xor(psum, 32);
        l_run += psum;

        // ---- P^T -> LDS via cvt_pk ----
#pragma unroll
        for (int mt = 0; mt < 4; ++mt) {
            i32x2 p;
            p[0] = cvtpk(st[mt][0], st[mt][1]);
            p[1] = cvtpk(st[mt][2], st[mt][3]);
            *(i32x2*)&Pt[(w * 16 + l16) * PADP + mt * 16 + quad * 4] = p;
        }

        // ---- O^T += V^T . P^T ----
        bf16x8 pf0 = *(const bf16x8*)&Pt[(w * 16 + l16) * PADP + quad * 8];
        bf16x8 pf1 = *(const bf16x8*)&Pt[(w * 16 + l16) * PADP + 32 + quad * 8];
        __builtin_amdgcn_s_setprio(1);
#pragma unroll
        for (int mt = 0; mt < 8; ++mt) {
            bf16x8 vf0 = *(const bf16x8*)&Vt[(mt * 16 + l16) * PADV + quad * 8];
            bf16x8 vf1 = *(const bf16x8*)&Vt[(mt * 16 + l16) * PADV + 32 + quad * 8];
            O[mt] = __builtin_amdgcn_mfma_f32_16x16x32_bf16(vf0, pf0, O[mt], 0, 0, 0);
            O[mt] = __builtin_amdgcn_mfma_f32_16x16x32_bf16(vf1, pf1, O[mt], 0, 0, 0);
        }
        __builtin_amdgcn_s_setprio(0);
    }

    // ---- partial epilogue: unnormalized O (bf16) + m,l (log2 domain) ----
    const int r = w * 16 + l16;
    const size_t jobbase = (size_t)b * NJOBS + jj;
    unsigned short* po = Opart + jobbase * (128 * 128) + (size_t)r * 128;
#pragma unroll
    for (int mt = 0; mt < 8; ++mt) {
        i32x2 p;
        p[0] = cvtpk(O[mt][0], O[mt][1]);
        p[1] = cvtpk(O[mt][2], O[mt][3]);
        *(i32x2*)&po[mt * 16 + quad * 4] = p;
    }
    if (quad == 0) {
        mbuf[jobbase * 128 + r] = m_run;
        lbuf[jobbase * 128 + r] = l_run;
    }

    // ---- split-K fixup: last job for q-tile (b,qi) combines & writes out ----
    __threadfence();                              // release partials (device scope)
    __syncthreads();                              // all partial stores issued
    if (t == 0) {
        unsigned int old = atomicAdd(&ctr[b * 32 + qi], 1u);   // device-scope (m20)
        lastFlag = (old == (unsigned)(nc - 1));
    }
    __syncthreads();
    if (!lastFlag) return;
    __threadfence();                              // acquire other jobs' partials

    {   // combine body (old combine_kernel, 512 thr): row=t>>2, cg=(t&3)*32
        const int row = t >> 2, cg = (t & 3) * 32;
        const int j0b = s;                        // first jj of this q-tile
        float mv[MAXC], lv[MAXC];
        float M = -1e30f;
#pragma unroll
        for (int c2 = 0; c2 < MAXC; ++c2) {
            if (c2 < nc) {
                const size_t jb = (size_t)b * NJOBS + j0b + c2;
                mv[c2] = mbuf[jb * 128 + row];
                lv[c2] = lbuf[jb * 128 + row];
                M = fmaxf(M, mv[c2]);
            } else { mv[c2] = -1e30f; lv[c2] = 0.f; }
        }
        float L = 0.f;
#pragma unroll
        for (int c2 = 0; c2 < MAXC; ++c2)
            if (c2 < nc) L += exp2f(mv[c2] - M) * lv[c2];
        const float Linv = 1.0f / L;

        float acc[32];
#pragma unroll
        for (int i = 0; i < 32; ++i) acc[i] = 0.f;
#pragma unroll
        for (int c2 = 0; c2 < MAXC; ++c2) {
            if (c2 < nc) {
                const float wgt = exp2f(mv[c2] - M) * Linv;
                const unsigned short* pp2 = Opart + ((size_t)b * NJOBS + j0b + c2) * (128 * 128) +
                                            (size_t)row * 128 + cg;
#pragma unroll
                for (int i = 0; i < 4; ++i) {
                    i32x4 d = *(const i32x4*)&pp2[i * 8];
#pragma unroll
                    for (int e = 0; e < 4; ++e) {
                        unsigned int u = (unsigned int)d[e];
                        acc[i * 8 + e * 2]     = fmaf(wgt, bf2f((unsigned short)(u & 0xffff)), acc[i * 8 + e * 2]);
                        acc[i * 8 + e * 2 + 1] = fmaf(wgt, bf2f((unsigned short)(u >> 16)),   acc[i * 8 + e * 2 + 1]);
                    }
                }
            }
        }
        float* op = out + ((size_t)b * SEQ + qi * 128 + row) * HD + cg;
#pragma unroll
        for (int i = 0; i < 8; ++i) {
            float4 res;
            res.x = acc[i * 4]; res.y = acc[i * 4 + 1];
            res.z = acc[i * 4 + 2]; res.w = acc[i * 4 + 3];
            *(float4*)&op[i * 4] = res;
        }
    }
}

extern "C" void kernel_launch(void* const* d_in, const int* in_sizes, int n_in,
                              void* d_out, int out_size, void* d_ws, size_t ws_size,
                              hipStream_t stream) {
    const float* x  = (const float*)d_in[0];
    const float* Wq = (const float*)d_in[1];
    const float* Wk = (const float*)d_in[2];
    const float* Wv = (const float*)d_in[3];

    unsigned short* qb    = (unsigned short*)d_ws;          // [16384][128] bf16
    unsigned short* kb    = qb  + (size_t)MROWS * HD;       // [16384][128] bf16
    unsigned short* vtb   = kb  + (size_t)MROWS * HD;       // [4][128][4096] bf16
    unsigned short* Wt    = vtb + (size_t)MROWS * HD;       // [24][32][64][8] bf16 frag-order
    unsigned short* Opart = Wt  + (size_t)3 * HD * EMB;     // [4][119][128][128] bf16
    float* mbuf = (float*)(Opart + (size_t)BATCH * NJOBS * 128 * 128);
    float* lbuf = mbuf + (size_t)BATCH * NJOBS * 128;
    unsigned int* ctr = (unsigned int*)(lbuf + (size_t)BATCH * NJOBS * 128);  // [4][32]
    float* out = (float*)d_out;

    hipMemsetAsync(ctr, 0, BATCH * 32 * sizeof(unsigned int), stream);
    wtrans_kernel <<<dim3(64, 3),  dim3(256), 0, stream>>>(Wq, Wk, Wv, Wt);
    qkv_kernel    <<<dim3(256),    dim3(512), 0, stream>>>(x, Wt, qb, kb, vtb);
    flash_kernel  <<<dim3(480),    dim3(512), 0, stream>>>(qb, kb, vtb, Opart, mbuf, lbuf, ctr, out);
}

// Round 8
// 167.221 us; speedup vs baseline: 2.0767x; 2.0767x over previous
//
#include <hip/hip_runtime.h>
#include <math.h>

#define BATCH 4
#define SEQ   4096
#define EMB   1024
#define HD    128
#define MROWS (BATCH*SEQ)
#define SCALE  0.08838834764831844f   // 1/sqrt(128)
#define SCALEQ 0.12751742f            // (1/sqrt(128)) * log2(e)  -> exp2-domain scores
#define CHUNK 10                      // kv-tiles (of 64) per split-KV job
#define NJOBS 119                     // jobs per batch at BQ=128, CHUNK=10
#define MAXC  7                       // max chunks per q-tile = ceil(64/10)

typedef __attribute__((ext_vector_type(8))) short bf16x8;   // MFMA A/B frag (4 VGPR)
typedef __attribute__((ext_vector_type(4))) short short4v;  // 8B LDS store
typedef __attribute__((ext_vector_type(4))) float f32x4;    // MFMA C/D frag
typedef __attribute__((ext_vector_type(4))) int   i32x4;    // 16B copy
typedef __attribute__((ext_vector_type(2))) int   i32x2;    // 8B copy

static __device__ __forceinline__ unsigned short f2bf(float f) {
    unsigned int u = __float_as_uint(f);
    u += 0x7fff + ((u >> 16) & 1);       // RNE
    return (unsigned short)(u >> 16);
}
static __device__ __forceinline__ float bf2f(unsigned short s) {
    return __uint_as_float((unsigned int)s << 16);
}
static __device__ __forceinline__ short4v pack4(float4 a) {
    short4v p;
    p[0] = (short)f2bf(a.x); p[1] = (short)f2bf(a.y);
    p[2] = (short)f2bf(a.z); p[3] = (short)f2bf(a.w);
    return p;
}
// HW packed f32->bf16 RNE
static __device__ __forceinline__ int cvtpk(float lo, float hi) {
    int r;
    asm("v_cvt_pk_bf16_f32 %0, %1, %2" : "=v"(r) : "v"(lo), "v"(hi));
    return r;
}
// async global->LDS, 16B/lane: dest = wave-uniform base + lane*16 (linear)
static __device__ __forceinline__ void gload_lds16(const unsigned short* g, unsigned short* l) {
    __builtin_amdgcn_global_load_lds(
        (const __attribute__((address_space(1))) void*)g,
        (__attribute__((address_space(3))) void*)l, 16, 0, 0);
}

// ---------------- W transpose + bf16 -> FRAGMENT-CONTIGUOUS layout ----------------
__global__ __launch_bounds__(256) void wtrans_kernel(
    const float* __restrict__ Wq, const float* __restrict__ Wk,
    const float* __restrict__ Wv, unsigned short* __restrict__ Wt)
{
    __shared__ __align__(16) unsigned short Xs[16 * 132];
    const int w  = blockIdx.y;
    const float* W = (w == 0) ? Wq : (w == 1) ? Wk : Wv;
    const float sc = (w == 0) ? SCALEQ : 1.0f;   // exp2-domain: scores carry log2(e)
    const int bx = blockIdx.x;
    const int k0 = bx * 16;
    const int t  = threadIdx.x;

#pragma unroll
    for (int i = 0; i < 2; ++i) {
        int gg = i * 256 + t;                 // 0..511
        int row = gg >> 5, c4 = gg & 31;
        float4 a = *(const float4*)&W[(size_t)(k0 + row) * HD + c4 * 4];
        short4v p;
        p[0] = (short)f2bf(a.x * sc); p[1] = (short)f2bf(a.y * sc);
        p[2] = (short)f2bf(a.z * sc); p[3] = (short)f2bf(a.w * sc);
        *(short4v*)&Xs[row * 132 + c4 * 4] = p;
    }
    __syncthreads();
    const int n = t >> 1, g = t & 1;
    i32x4 o;
#pragma unroll
    for (int e = 0; e < 4; ++e) {
        unsigned int lo = Xs[(g * 8 + e * 2    ) * 132 + n];
        unsigned int hi = Xs[(g * 8 + e * 2 + 1) * 132 + n];
        o[e] = (int)(lo | (hi << 16));
    }
    const int ntg  = w * 8 + (n >> 4);
    const int kc   = bx >> 1;
    const int quad = (bx * 2 + g) & 3;
    const int lane = quad * 16 + (n & 15);
    *(i32x4*)&Wt[(((size_t)ntg * 32 + kc) * 64 + lane) * 8] = o;
}

// ---------------- Fused QKV (unchanged from round 5) ----------------
__global__ __launch_bounds__(512, 2) void qkv_kernel(
    const float* __restrict__ x, const unsigned short* __restrict__ Wt,
    unsigned short* __restrict__ qb, unsigned short* __restrict__ kb,
    unsigned short* __restrict__ vtb)
{
    __shared__ __align__(1024) unsigned short lds[58368];  // W dbuf 96KB + x dbuf 18.4KB
    unsigned short* Ws  = lds;
    unsigned short* xsA = lds + 49152;
    unsigned short* xsB = lds + 53760;

    const int t    = threadIdx.x;
    const int lane = t & 63, ng = t >> 6;
    const int quad = lane >> 4, l16 = lane & 15;
    const int m0   = blockIdx.x * 64;

    f32x4 acc[4][3];
#pragma unroll
    for (int i = 0; i < 4; ++i)
#pragma unroll
        for (int j = 0; j < 3; ++j) acc[i][j] = (f32x4){0.f, 0.f, 0.f, 0.f};

    const int xr0 = t >> 4,         xc0 = (t & 15) * 4;
    const int xr1 = (t + 512) >> 4, xc1 = ((t + 512) & 15) * 4;
    const float* xb0 = x + (size_t)(m0 + xr0) * EMB + xc0;
    const float* xb1 = x + (size_t)(m0 + xr1) * EMB + xc1;

    const unsigned short* Wg = Wt + (size_t)lane * 8;
    float4 xra, xrb;

    {
        float4 a = *(const float4*)&xb0[0];
        float4 b = *(const float4*)&xb1[0];
        *(short4v*)&xsA[xr0 * 72 + xc0] = pack4(a);
        *(short4v*)&xsA[xr1 * 72 + xc1] = pack4(b);
#pragma unroll
        for (int jt = 0; jt < 3; ++jt)
#pragma unroll
            for (int kcl = 0; kcl < 2; ++kcl) {
                int ntg = ng * 3 + jt;
                gload_lds16(Wg + ((size_t)ntg * 32 + kcl) * 512,
                            Ws + ((size_t)ntg * 2 + kcl) * 512);
            }
        xra = *(const float4*)&xb0[64];
        xrb = *(const float4*)&xb1[64];
    }
    asm volatile("s_waitcnt vmcnt(2)" ::: "memory");
    asm volatile("s_waitcnt lgkmcnt(0)" ::: "memory");
    __builtin_amdgcn_s_barrier();

    for (int ph = 0; ph < 16; ++ph) {
        const int cb = ph & 1, nb = cb ^ 1;
        unsigned short* xc = cb ? xsB : xsA;
        unsigned short* xn = cb ? xsA : xsB;
        const int kcn = (ph < 15 ? ph + 1 : 15) * 2;

#pragma unroll
        for (int jt = 0; jt < 3; ++jt)
#pragma unroll
            for (int kcl = 0; kcl < 2; ++kcl) {
                int ntg = ng * 3 + jt;
                gload_lds16(Wg + ((size_t)ntg * 32 + kcn + kcl) * 512,
                            Ws + ((size_t)(nb * 48) + ntg * 2 + kcl) * 512);
            }
        *(short4v*)&xn[xr0 * 72 + xc0] = pack4(xra);
        *(short4v*)&xn[xr1 * 72 + xc1] = pack4(xrb);
        {
            const int xcol = (ph + 2 < 16) ? (ph + 2) * 64 : 960;
            xra = *(const float4*)&xb0[xcol];
            xrb = *(const float4*)&xb1[xcol];
        }
        {
            bf16x8 aA[2][4], aB[2][3];
#pragma unroll
            for (int ks = 0; ks < 2; ++ks)
#pragma unroll
                for (int jt = 0; jt < 3; ++jt)
                    aB[ks][jt] = *(const bf16x8*)&Ws[((size_t)(cb * 48) + (ng * 3 + jt) * 2 + ks) * 512 + lane * 8];
#pragma unroll
            for (int ks = 0; ks < 2; ++ks)
#pragma unroll
                for (int mt = 0; mt < 4; ++mt)
                    aA[ks][mt] = *(const bf16x8*)&xc[(mt * 16 + l16) * 72 + ks * 32 + quad * 8];
            __builtin_amdgcn_s_setprio(1);
#pragma unroll
            for (int ks = 0; ks < 2; ++ks)
#pragma unroll
                for (int mt = 0; mt < 4; ++mt)
#pragma unroll
                    for (int jt = 0; jt < 3; ++jt)
                        acc[mt][jt] = __builtin_amdgcn_mfma_f32_16x16x32_bf16(
                            aA[ks][mt], aB[ks][jt], acc[mt][jt], 0, 0, 0);
            __builtin_amdgcn_s_setprio(0);
        }
        asm volatile("s_waitcnt vmcnt(2)" ::: "memory");
        asm volatile("s_waitcnt lgkmcnt(0)" ::: "memory");
        __builtin_amdgcn_s_barrier();
    }

    // ---- epilogue ----
    unsigned short* Cq = lds;                 // [64][136]
    unsigned short* Ck = lds + 64 * 136;      // [64][136]
    unsigned short* Cv = lds + 2 * 64 * 136;  // [128][72] transposed
#pragma unroll
    for (int mt = 0; mt < 4; ++mt)
#pragma unroll
        for (int jt = 0; jt < 3; ++jt) {
            int nt = ng * 3 + jt;
            int wm = nt >> 3, nl = nt & 7;
            if (wm < 2) {
                unsigned short* C = (wm == 0) ? Cq : Ck;
#pragma unroll
                for (int rr = 0; rr < 4; ++rr)
                    C[(mt * 16 + quad * 4 + rr) * 136 + nl * 16 + l16] =
                        f2bf(acc[mt][jt][rr]);
            } else {
                i32x2 p;
                p[0] = cvtpk(acc[mt][jt][0], acc[mt][jt][1]);
                p[1] = cvtpk(acc[mt][jt][2], acc[mt][jt][3]);
                *(i32x2*)&Cv[(nl * 16 + l16) * 72 + mt * 16 + quad * 4] = p;
            }
        }
    __syncthreads();
    {
#pragma unroll
        for (int i = 0; i < 2; ++i) {
            int idx = i * 512 + t;
            int row = idx >> 4, seg = idx & 15;
            *(i32x4*)&qb[((size_t)(m0 + row)) * HD + seg * 8] = *(const i32x4*)&Cq[row * 136 + seg * 8];
            *(i32x4*)&kb[((size_t)(m0 + row)) * HD + seg * 8] = *(const i32x4*)&Ck[row * 136 + seg * 8];
        }
    }
    {
        const int b = m0 >> 12, s0 = m0 & 4095;
#pragma unroll
        for (int i = 0; i < 2; ++i) {
            int idx = i * 512 + t;
            int h = idx >> 3, seg = idx & 7;
            *(i32x4*)&vtb[(size_t)b * (HD * SEQ) + (size_t)h * SEQ + s0 + seg * 8] =
                *(const i32x4*)&Cv[h * 72 + seg * 8];
        }
    }
}

// ---------------- Flash attention (exact round-5 version; round-7 fused combine reverted:
// device-scope fence forced cross-XCD L2 writeback -> partials re-read from HBM, 6x slower) ----
#define PADK 136
#define PADV 72
#define PADP 72
#define DEFER_THR 8.0f   // log2 domain: P bounded by 2^8=256, safe in bf16/f32

__global__ __launch_bounds__(512, 4) void flash_kernel(
    const unsigned short* __restrict__ qb, const unsigned short* __restrict__ kb,
    const unsigned short* __restrict__ vtb, unsigned short* __restrict__ Opart,
    float* __restrict__ mbuf, float* __restrict__ lbuf)
{
    __shared__ __align__(16) unsigned short Ks[64 * PADK];    // 17.4 KB
    __shared__ __align__(16) unsigned short Vt[128 * PADV];   // 18.4 KB
    __shared__ __align__(16) unsigned short Pt[128 * PADP];   // 18.4 KB

    const int bx   = blockIdx.x;
    const int slot = bx & 7, pp = bx >> 3;
    const int b    = slot >> 1;
    const int jj   = pp * 2 + (slot & 1);
    if (jj >= NJOBS) return;

    const int t    = threadIdx.x;
    const int lane = t & 63, w = t >> 6;     // 8 waves
    const int quad = lane >> 4, l16 = lane & 15;

    int qi = 0, s = 0;
    for (qi = 0; qi < 32; ++qi) {
        int cnt = (qi + 5) / 5;
        if (jj < s + cnt) break;
        s += cnt;
    }
    const int c    = jj - s;
    const int qrow = qi * 128 + w * 16 + l16;
    const int jmax = 2 * qi + 2;
    const int jbeg = c * CHUNK;
    const int jend = min(jbeg + CHUNK, jmax);
    const int wtop = qi * 128 + w * 16;

    bf16x8 qf[4];
    {
        const unsigned short* qp = qb + ((size_t)b * SEQ + qrow) * HD;
#pragma unroll
        for (int ks = 0; ks < 4; ++ks)
            qf[ks] = *(const bf16x8*)&qp[ks * 32 + quad * 8];
    }

    f32x4 O[8];
#pragma unroll
    for (int i = 0; i < 8; ++i) O[i] = (f32x4){0.f, 0.f, 0.f, 0.f};
    float m_run = -1e30f, l_run = 0.f;

    const unsigned short* kbb  = kb  + (size_t)b * SEQ * HD;
    const unsigned short* vtbb = vtb + (size_t)b * HD * SEQ;

    const int gg0 = t, gg1 = 512 + t;
    i32x4 kr0, kr1, vr0, vr1;
    kr0 = *(const i32x4*)&kbb[(size_t)jbeg * 64 * HD + (size_t)gg0 * 8];
    kr1 = *(const i32x4*)&kbb[(size_t)jbeg * 64 * HD + (size_t)gg1 * 8];
    vr0 = *(const i32x4*)&vtbb[(size_t)(gg0 >> 3) * SEQ + jbeg * 64 + (gg0 & 7) * 8];
    vr1 = *(const i32x4*)&vtbb[(size_t)(gg1 >> 3) * SEQ + jbeg * 64 + (gg1 & 7) * 8];

    for (int j0 = jbeg; j0 < jend; ++j0) {
        __syncthreads();   // prior iteration's reads of Ks/Vt complete (WAR)
        *(i32x4*)&Ks[(gg0 >> 4) * PADK + (gg0 & 15) * 8] = kr0;
        *(i32x4*)&Ks[(gg1 >> 4) * PADK + (gg1 & 15) * 8] = kr1;
        *(i32x4*)&Vt[(gg0 >> 3) * PADV + (gg0 & 7) * 8] = vr0;
        *(i32x4*)&Vt[(gg1 >> 3) * PADV + (gg1 & 7) * 8] = vr1;
        __syncthreads();

        if (j0 + 1 < jend) {
            const int j1 = j0 + 1;
            kr0 = *(const i32x4*)&kbb[(size_t)j1 * 64 * HD + (size_t)gg0 * 8];
            kr1 = *(const i32x4*)&kbb[(size_t)j1 * 64 * HD + (size_t)gg1 * 8];
            vr0 = *(const i32x4*)&vtbb[(size_t)(gg0 >> 3) * SEQ + j1 * 64 + (gg0 & 7) * 8];
            vr1 = *(const i32x4*)&vtbb[(size_t)(gg1 >> 3) * SEQ + j1 * 64 + (gg1 & 7) * 8];
        }

        if (j0 * 64 > wtop + 15) continue;

        // ---- S^T = K . Q^T ----
        f32x4 st[4];
        __builtin_amdgcn_s_setprio(1);
#pragma unroll
        for (int mt = 0; mt < 4; ++mt) {
            f32x4 a = (f32x4){0.f, 0.f, 0.f, 0.f};
#pragma unroll
            for (int ks = 0; ks < 4; ++ks) {
                bf16x8 kf = *(const bf16x8*)&Ks[(mt * 16 + l16) * PADK + ks * 32 + quad * 8];
                a = __builtin_amdgcn_mfma_f32_16x16x32_bf16(kf, qf[ks], a, 0, 0, 0);
            }
            st[mt] = a;
        }
        __builtin_amdgcn_s_setprio(0);

        // ---- causal mask ----
        if (j0 * 64 + 63 > wtop) {
#pragma unroll
            for (int mt = 0; mt < 4; ++mt)
#pragma unroll
                for (int rr = 0; rr < 4; ++rr) {
                    int kv = j0 * 64 + mt * 16 + quad * 4 + rr;
                    if (kv > qrow) st[mt][rr] = -1e30f;
                }
        }

        // ---- online softmax, exp2 domain ----
        float mx = -1e30f;
#pragma unroll
        for (int mt = 0; mt < 4; ++mt)
#pragma unroll
            for (int rr = 0; rr < 4; ++rr) mx = fmaxf(mx, st[mt][rr]);
        mx = fmaxf(mx, __shfl_xor(mx, 16));
        mx = fmaxf(mx, __shfl_xor(mx, 32));
        if (!__all(mx <= m_run + DEFER_THR)) {
            const float m_new = fmaxf(m_run, mx);
            const float alpha = exp2f(m_run - m_new);
            l_run *= alpha;
#pragma unroll
            for (int i = 0; i < 8; ++i) {
                O[i][0] *= alpha; O[i][1] *= alpha; O[i][2] *= alpha; O[i][3] *= alpha;
            }
            m_run = m_new;
        }
        float psum = 0.f;
#pragma unroll
        for (int mt = 0; mt < 4; ++mt)
#pragma unroll
            for (int rr = 0; rr < 4; ++rr) {
                float p = exp2f(st[mt][rr] - m_run);
                st[mt][rr] = p;
                psum += p;
            }
        psum += __shfl_xor(psum, 16);
        psum += __shfl_xor(psum, 32);
        l_run += psum;

        // ---- P^T -> LDS via cvt_pk ----
#pragma unroll
        for (int mt = 0; mt < 4; ++mt) {
            i32x2 p;
            p[0] = cvtpk(st[mt][0], st[mt][1]);
            p[1] = cvtpk(st[mt][2], st[mt][3]);
            *(i32x2*)&Pt[(w * 16 + l16) * PADP + mt * 16 + quad * 4] = p;
        }

        // ---- O^T += V^T . P^T ----
        bf16x8 pf0 = *(const bf16x8*)&Pt[(w * 16 + l16) * PADP + quad * 8];
        bf16x8 pf1 = *(const bf16x8*)&Pt[(w * 16 + l16) * PADP + 32 + quad * 8];
        __builtin_amdgcn_s_setprio(1);
#pragma unroll
        for (int mt = 0; mt < 8; ++mt) {
            bf16x8 vf0 = *(const bf16x8*)&Vt[(mt * 16 + l16) * PADV + quad * 8];
            bf16x8 vf1 = *(const bf16x8*)&Vt[(mt * 16 + l16) * PADV + 32 + quad * 8];
            O[mt] = __builtin_amdgcn_mfma_f32_16x16x32_bf16(vf0, pf0, O[mt], 0, 0, 0);
            O[mt] = __builtin_amdgcn_mfma_f32_16x16x32_bf16(vf1, pf1, O[mt], 0, 0, 0);
        }
        __builtin_amdgcn_s_setprio(0);
    }

    // ---- partial epilogue: unnormalized O (bf16, cvt_pk) + m,l (log2 domain) ----
    const int r = w * 16 + l16;
    const size_t jobbase = (size_t)b * NJOBS + jj;
    unsigned short* po = Opart + jobbase * (128 * 128) + (size_t)r * 128;
#pragma unroll
    for (int mt = 0; mt < 8; ++mt) {
        i32x2 p;
        p[0] = cvtpk(O[mt][0], O[mt][1]);
        p[1] = cvtpk(O[mt][2], O[mt][3]);
        *(i32x2*)&po[mt * 16 + quad * 4] = p;
    }
    if (quad == 0) {
        mbuf[jobbase * 128 + r] = m_run;
        lbuf[jobbase * 128 + r] = l_run;
    }
}

// ---------------- Combine partials (log2-domain m) — round-8 re-parallelized ----------------
// grid (32, 4, 2) x 512 thr (2x blocks vs R5, half the per-thread serial work):
// block z-half covers 64 rows; thread -> row = bz*64 + (t>>3), 16 head cols at (t&7)*16.
// Rationale: combine has never been directly visible (<41.8us bound only); residual
// accounting says combine+gaps ~ 83us. This isolates it: if total drops, combine was
// the hidden cost (it was latency-bound at 128 blocks / 4 waves/CU).
__global__ __launch_bounds__(512) void combine_kernel(
    const unsigned short* __restrict__ Opart, const float* __restrict__ mbuf,
    const float* __restrict__ lbuf, float* __restrict__ out)
{
    const int qi = blockIdx.x, b = blockIdx.y;
    const int nc = (qi + 5) / 5;
    int j0 = 0;
    for (int q = 0; q < qi; ++q) j0 += (q + 5) / 5;
    const int t = threadIdx.x;
    const int row = blockIdx.z * 64 + (t >> 3);
    const int cg  = (t & 7) * 16;

    float mv[MAXC], lv[MAXC];
    float M = -1e30f;
#pragma unroll
    for (int c2 = 0; c2 < MAXC; ++c2) {
        if (c2 < nc) {
            const size_t jb = (size_t)b * NJOBS + j0 + c2;
            mv[c2] = mbuf[jb * 128 + row];
            lv[c2] = lbuf[jb * 128 + row];
            M = fmaxf(M, mv[c2]);
        } else { mv[c2] = -1e30f; lv[c2] = 0.f; }
    }
    float L = 0.f;
#pragma unroll
    for (int c2 = 0; c2 < MAXC; ++c2)
        if (c2 < nc) L += exp2f(mv[c2] - M) * lv[c2];
    const float Linv = 1.0f / L;

    float acc[16];
#pragma unroll
    for (int i = 0; i < 16; ++i) acc[i] = 0.f;
#pragma unroll
    for (int c2 = 0; c2 < MAXC; ++c2) {
        if (c2 < nc) {
            const float wgt = exp2f(mv[c2] - M) * Linv;
            const unsigned short* po = Opart + ((size_t)b * NJOBS + j0 + c2) * (128 * 128) +
                                       (size_t)row * 128 + cg;
#pragma unroll
            for (int i = 0; i < 2; ++i) {
                i32x4 d = *(const i32x4*)&po[i * 8];
#pragma unroll
                for (int e = 0; e < 4; ++e) {
                    unsigned int u = (unsigned int)d[e];
                    acc[i * 8 + e * 2]     = fmaf(wgt, bf2f((unsigned short)(u & 0xffff)), acc[i * 8 + e * 2]);
                    acc[i * 8 + e * 2 + 1] = fmaf(wgt, bf2f((unsigned short)(u >> 16)),   acc[i * 8 + e * 2 + 1]);
                }
            }
        }
    }
    float* op = out + ((size_t)b * SEQ + qi * 128 + row) * HD + cg;
#pragma unroll
    for (int i = 0; i < 4; ++i) {
        float4 res;
        res.x = acc[i * 4]; res.y = acc[i * 4 + 1];
        res.z = acc[i * 4 + 2]; res.w = acc[i * 4 + 3];
        *(float4*)&op[i * 4] = res;
    }
}

extern "C" void kernel_launch(void* const* d_in, const int* in_sizes, int n_in,
                              void* d_out, int out_size, void* d_ws, size_t ws_size,
                              hipStream_t stream) {
    const float* x  = (const float*)d_in[0];
    const float* Wq = (const float*)d_in[1];
    const float* Wk = (const float*)d_in[2];
    const float* Wv = (const float*)d_in[3];

    unsigned short* qb    = (unsigned short*)d_ws;          // [16384][128] bf16
    unsigned short* kb    = qb  + (size_t)MROWS * HD;       // [16384][128] bf16
    unsigned short* vtb   = kb  + (size_t)MROWS * HD;       // [4][128][4096] bf16
    unsigned short* Wt    = vtb + (size_t)MROWS * HD;       // [24][32][64][8] bf16 frag-order
    unsigned short* Opart = Wt  + (size_t)3 * HD * EMB;     // [4][119][128][128] bf16
    float* mbuf = (float*)(Opart + (size_t)BATCH * NJOBS * 128 * 128);
    float* lbuf = mbuf + (size_t)BATCH * NJOBS * 128;
    float* out = (float*)d_out;

    wtrans_kernel <<<dim3(64, 3),    dim3(256), 0, stream>>>(Wq, Wk, Wv, Wt);
    qkv_kernel    <<<dim3(256),      dim3(512), 0, stream>>>(x, Wt, qb, kb, vtb);
    flash_kernel  <<<dim3(480),      dim3(512), 0, stream>>>(qb, kb, vtb, Opart, mbuf, lbuf);
    combine_kernel<<<dim3(32, 4, 2), dim3(512), 0, stream>>>(Opart, mbuf, lbuf, out);
}